// Round 1
// baseline (3131.482 us; speedup 1.0000x reference)
//
#include <hip/hip_runtime.h>
#include <float.h>
#include <math.h>

#define N_ROWS 32768
#define DIN    360
#define HID    512
#define MSLOTS 1024

// ---------------- generic f32 GEMM: C = epilogue(A @ B) ----------------
// A [M x K] row-major. B: TRANSB ? [N x K] (use rows as cols) : [K x N].
// BK=8; all of M,N multiples of 64 and K multiple of 8 (360/512/1024). No guards.
template<bool TRANSB, bool BIAS, bool RELU, bool HMUL>
__global__ __launch_bounds__(256) void gemm_f32(
    const float* __restrict__ A, const float* __restrict__ B,
    const float* __restrict__ bias, const float* __restrict__ hm,
    float* __restrict__ C, int M, int N, int K)
{
    __shared__ float As[8][64];
    __shared__ float Bs[8][64];
    const int tid = threadIdx.x;
    const int tx = tid & 15, ty = tid >> 4;
    const int m0 = blockIdx.x * 64, n0 = blockIdx.y * 64;
    const int arow = tid >> 2, ac = (tid & 3) * 2;   // 64x8 staging pattern
    float acc[4][4] = {};
    for (int k0 = 0; k0 < K; k0 += 8) {
        float2 av = *(const float2*)(A + (size_t)(m0 + arow) * K + k0 + ac);
        As[ac][arow] = av.x; As[ac + 1][arow] = av.y;
        if (TRANSB) {
            float2 bv = *(const float2*)(B + (size_t)(n0 + arow) * K + k0 + ac);
            Bs[ac][arow] = bv.x; Bs[ac + 1][arow] = bv.y;
        } else {
            const int br = tid >> 5, bc = (tid & 31) * 2;
            float2 bv = *(const float2*)(B + (size_t)(k0 + br) * N + n0 + bc);
            Bs[br][bc] = bv.x; Bs[br][bc + 1] = bv.y;
        }
        __syncthreads();
        #pragma unroll
        for (int k = 0; k < 8; ++k) {
            float a[4], b[4];
            #pragma unroll
            for (int i = 0; i < 4; ++i) a[i] = As[k][ty * 4 + i];
            #pragma unroll
            for (int j = 0; j < 4; ++j) b[j] = Bs[k][tx * 4 + j];
            #pragma unroll
            for (int i = 0; i < 4; ++i)
                #pragma unroll
                for (int j = 0; j < 4; ++j)
                    acc[i][j] = fmaf(a[i], b[j], acc[i][j]);
        }
        __syncthreads();
    }
    #pragma unroll
    for (int i = 0; i < 4; ++i) {
        const int row = m0 + ty * 4 + i;
        const int col0 = n0 + tx * 4;
        float4 o;
        float* po = &o.x;
        #pragma unroll
        for (int j = 0; j < 4; ++j) {
            float v = acc[i][j];
            if (BIAS) v += bias[col0 + j];
            if (RELU) v = fmaxf(v, 0.0f);
            po[j] = v;
        }
        if (HMUL) {
            float4 hv = *(const float4*)(hm + (size_t)row * N + col0);
            o.x *= hv.x; o.y *= hv.y; o.z *= hv.z; o.w *= hv.w;
        }
        *(float4*)(C + (size_t)row * N + col0) = o;
    }
}

// ---------------- row softmax (axis=1) of +score and -score ----------------
// also: g[row] = argmax (first-index tie-break), rowmax[row] = max score.
__global__ __launch_bounds__(256) void row_softmax(
    const float* __restrict__ score, float* __restrict__ sm, float* __restrict__ usm,
    int* __restrict__ g, float* __restrict__ rowmax)
{
    const int row = blockIdx.x, t = threadIdx.x;
    const float4 v = ((const float4*)(score + (size_t)row * MSLOTS))[t];
    float mx = v.x; int mi = t * 4;
    if (v.y > mx) { mx = v.y; mi = t * 4 + 1; }
    if (v.z > mx) { mx = v.z; mi = t * 4 + 2; }
    if (v.w > mx) { mx = v.w; mi = t * 4 + 3; }
    float mn = fminf(fminf(v.x, v.y), fminf(v.z, v.w));
    __shared__ float rf[256]; __shared__ int ri[256]; __shared__ float rn[256];
    rf[t] = mx; ri[t] = mi; rn[t] = mn;
    __syncthreads();
    for (int s = 128; s > 0; s >>= 1) {
        if (t < s) {
            float o = rf[t + s]; int oi = ri[t + s];
            if (o > rf[t] || (o == rf[t] && oi < ri[t])) { rf[t] = o; ri[t] = oi; }
            rn[t] = fminf(rn[t], rn[t + s]);
        }
        __syncthreads();
    }
    const float rmx = rf[0]; const int gi = ri[0]; const float rmn = rn[0];
    __syncthreads();
    const float e0 = expf(v.x - rmx), e1 = expf(v.y - rmx), e2 = expf(v.z - rmx), e3 = expf(v.w - rmx);
    const float u0 = expf(rmn - v.x), u1 = expf(rmn - v.y), u2 = expf(rmn - v.z), u3 = expf(rmn - v.w);
    rf[t] = e0 + e1 + e2 + e3; rn[t] = u0 + u1 + u2 + u3;
    __syncthreads();
    for (int s = 128; s > 0; s >>= 1) {
        if (t < s) { rf[t] += rf[t + s]; rn[t] += rn[t + s]; }
        __syncthreads();
    }
    const float isp = 1.0f / rf[0], isn = 1.0f / rn[0];
    const float4 so = make_float4(e0 * isp, e1 * isp, e2 * isp, e3 * isp);
    const float4 uo = make_float4(u0 * isn, u1 * isn, u2 * isn, u3 * isn);
    ((float4*)(sm + (size_t)row * MSLOTS))[t] = so;
    ((float4*)(usm + (size_t)row * MSLOTS))[t] = uo;
    if (t == 0) { g[row] = gi; rowmax[row] = rmx; }
}

// ---------------- column (axis=0) stats: pass A min/max partials ----------------
__global__ __launch_bounds__(256) void col_minmax(
    const float* __restrict__ score, float* __restrict__ pmax, float* __restrict__ pmin)
{
    const int c = threadIdx.x & 63;
    const int col = blockIdx.x * 64 + c;
    const int tr = threadIdx.x >> 6;
    const int row0 = blockIdx.y * 1024;
    float mx = -FLT_MAX, mn = FLT_MAX;
    for (int k = 0; k < 256; ++k) {
        const float s = score[(size_t)(row0 + tr + k * 4) * MSLOTS + col];
        mx = fmaxf(mx, s); mn = fminf(mn, s);
    }
    __shared__ float smx[4][64], smn[4][64];
    smx[tr][c] = mx; smn[tr][c] = mn;
    __syncthreads();
    if (tr == 0) {
        #pragma unroll
        for (int i = 1; i < 4; ++i) { mx = fmaxf(mx, smx[i][c]); mn = fminf(mn, smn[i][c]); }
        pmax[(size_t)blockIdx.y * MSLOTS + col] = mx;
        pmin[(size_t)blockIdx.y * MSLOTS + col] = mn;
    }
}

__global__ __launch_bounds__(256) void col_stage2_minmax(
    const float* __restrict__ pmax, const float* __restrict__ pmin,
    float* __restrict__ m_pos, float* __restrict__ m_neg)
{
    const int col = blockIdx.x * 256 + threadIdx.x;
    float mx = -FLT_MAX, mn = FLT_MAX;
    for (int k = 0; k < 32; ++k) {
        mx = fmaxf(mx, pmax[(size_t)k * MSLOTS + col]);
        mn = fminf(mn, pmin[(size_t)k * MSLOTS + col]);
    }
    m_pos[col] = mx;
    m_neg[col] = -mn;   // max of (-score) over the column
}

// ---------------- column stats: pass B exp-sums ----------------
__global__ __launch_bounds__(256) void col_sum(
    const float* __restrict__ score, const float* __restrict__ m_pos,
    const float* __restrict__ m_neg, float* __restrict__ psum, float* __restrict__ pnsum)
{
    const int c = threadIdx.x & 63;
    const int col = blockIdx.x * 64 + c;
    const int tr = threadIdx.x >> 6;
    const int row0 = blockIdx.y * 1024;
    const float mp = m_pos[col], mg = m_neg[col];
    float sp = 0.f, sn = 0.f;
    for (int k = 0; k < 256; ++k) {
        const float s = score[(size_t)(row0 + tr + k * 4) * MSLOTS + col];
        sp += expf(s - mp);
        sn += expf(-s - mg);
    }
    __shared__ float s1[4][64], s2[4][64];
    s1[tr][c] = sp; s2[tr][c] = sn;
    __syncthreads();
    if (tr == 0) {
        #pragma unroll
        for (int i = 1; i < 4; ++i) { sp += s1[i][c]; sn += s2[i][c]; }
        psum [(size_t)blockIdx.y * MSLOTS + col] = sp;
        pnsum[(size_t)blockIdx.y * MSLOTS + col] = sn;
    }
}

__global__ __launch_bounds__(256) void col_stage2_sum(
    const float* __restrict__ ps, const float* __restrict__ pn,
    float* __restrict__ s_pos, float* __restrict__ s_neg)
{
    const int col = blockIdx.x * 256 + threadIdx.x;
    float a = 0.f, b = 0.f;
    for (int k = 0; k < 32; ++k) { a += ps[(size_t)k * MSLOTS + col]; b += pn[(size_t)k * MSLOTS + col]; }
    s_pos[col] = a; s_neg[col] = b;
}

// ---------------- write usq and sq (sq in-place over score) ----------------
__global__ __launch_bounds__(256) void col_write(
    float* __restrict__ score_sq, float* __restrict__ usq,
    const float* __restrict__ m_pos, const float* __restrict__ s_pos,
    const float* __restrict__ m_neg, const float* __restrict__ s_neg)
{
    const size_t idx = (size_t)blockIdx.x * 256 + threadIdx.x;  // float4 index
    const int col = (int)((idx & 255) * 4);
    const float4 s = ((const float4*)score_sq)[idx];
    float4 q, uq;
    q.x  = expf( s.x - m_pos[col + 0]) / s_pos[col + 0];
    q.y  = expf( s.y - m_pos[col + 1]) / s_pos[col + 1];
    q.z  = expf( s.z - m_pos[col + 2]) / s_pos[col + 2];
    q.w  = expf( s.w - m_pos[col + 3]) / s_pos[col + 3];
    uq.x = expf(-s.x - m_neg[col + 0]) / s_neg[col + 0];
    uq.y = expf(-s.y - m_neg[col + 1]) / s_neg[col + 1];
    uq.z = expf(-s.z - m_neg[col + 2]) / s_neg[col + 2];
    uq.w = expf(-s.w - m_neg[col + 3]) / s_neg[col + 3];
    ((float4*)usq)[idx] = uq;
    ((float4*)score_sq)[idx] = q;
}

// ---------------- top-1 weighted scatter: qu[g[i]] += w_i * h[i] ----------------
// w_i = sq[i,g_i]/colmax(sq)[g_i] = exp(rowmax_i - m_pos[g_i])
__global__ __launch_bounds__(256) void scatter_qu(
    const float* __restrict__ h, const int* __restrict__ g,
    const float* __restrict__ rowmax, const float* __restrict__ m_pos,
    float* __restrict__ qu)
{
    const int row = blockIdx.x, t = threadIdx.x;
    const int gi = g[row];
    const float w = expf(rowmax[row] - m_pos[gi]);
    const float2 hv = ((const float2*)(h + (size_t)row * HID))[t];
    atomicAdd(&qu[(size_t)gi * HID + t * 2 + 0], w * hv.x);
    atomicAdd(&qu[(size_t)gi * HID + t * 2 + 1], w * hv.y);
}

// ---------------- new_mem = (qu + K) / max(||qu+K||, 1e-12) ----------------
__global__ __launch_bounds__(256) void norm_mem(
    const float* __restrict__ qu, const float* __restrict__ Km, float* __restrict__ nm)
{
    const int j = blockIdx.x, t = threadIdx.x;
    const float2 q = ((const float2*)(qu + (size_t)j * HID))[t];
    const float2 k = ((const float2*)(Km + (size_t)j * HID))[t];
    const float vx = q.x + k.x, vy = q.y + k.y;
    __shared__ float red[256];
    red[t] = vx * vx + vy * vy;
    __syncthreads();
    for (int s = 128; s > 0; s >>= 1) {
        if (t < s) red[t] += red[t + s];
        __syncthreads();
    }
    const float inv = 1.0f / fmaxf(sqrtf(red[0]), 1e-12f);
    ((float2*)(nm + (size_t)j * HID))[t] = make_float2(vx * inv, vy * inv);
}

// ---------------- pred = h @ Wd + bd ----------------
__global__ __launch_bounds__(256) void pred_k(
    const float* __restrict__ h, const float* __restrict__ Wd,
    const float* __restrict__ bd, float* __restrict__ pred)
{
    const int lane = threadIdx.x & 63, wv = threadIdx.x >> 6;
    const int row = blockIdx.x * 4 + wv;
    const float* hr = h + (size_t)row * HID + lane * 8;
    const float* wr = Wd + lane * 8;
    float a = 0.f;
    #pragma unroll
    for (int k = 0; k < 8; ++k) a = fmaf(hr[k], wr[k], a);
    for (int o = 32; o > 0; o >>= 1) a += __shfl_down(a, o, 64);
    if (lane == 0) pred[row] = a + bd[0];
}

extern "C" void kernel_launch(void* const* d_in, const int* in_sizes, int n_in,
                              void* d_out, int out_size, void* d_ws, size_t ws_size,
                              hipStream_t stream)
{
    const float* x  = (const float*)d_in[0];
    const float* Km = (const float*)d_in[1];
    const float* W0 = (const float*)d_in[2];
    const float* b0 = (const float*)d_in[3];
    const float* W1 = (const float*)d_in[4];
    const float* b1 = (const float*)d_in[5];
    const float* W2 = (const float*)d_in[6];
    const float* b2 = (const float*)d_in[7];
    const float* Wd = (const float*)d_in[8];
    const float* bd = (const float*)d_in[9];

    float* out      = (float*)d_out;
    float* pred     = out;
    float* upd_n    = out + 32768;
    float* usq      = upd_n + (size_t)N_ROWS * HID;
    float* usm      = usq   + (size_t)N_ROWS * MSLOTS;
    float* upd_p    = usm   + (size_t)N_ROWS * MSLOTS;
    float* sq       = upd_p + (size_t)N_ROWS * HID;     // holds score until col_write
    float* sm       = sq    + (size_t)N_ROWS * MSLOTS;
    float* new_mem  = sm    + (size_t)N_ROWS * MSLOTS;

    float* ws     = (float*)d_ws;
    float* h      = ws;                                  // [N_ROWS*HID]
    float* pA     = h + (size_t)N_ROWS * HID;            // [32*MSLOTS]
    float* pB     = pA + 32 * MSLOTS;                    // [32*MSLOTS]
    float* m_pos  = pB + 32 * MSLOTS;                    // [MSLOTS]
    float* s_pos  = m_pos + MSLOTS;
    float* m_neg  = s_pos + MSLOTS;
    float* s_neg  = m_neg + MSLOTS;
    float* rowmax = s_neg + MSLOTS;                      // [N_ROWS]
    int*   g      = (int*)(rowmax + N_ROWS);             // [N_ROWS]
    float* qu     = (float*)(g + N_ROWS);                // [MSLOTS*HID]

    const dim3 blk(256);

    // MLP: h0 -> upd_p region (temp), h1 -> upd_n region (temp), h -> ws
    gemm_f32<false, true,  true,  false><<<dim3(512,  8), blk, 0, stream>>>(x,     W0, b0, nullptr, upd_p, N_ROWS, HID,    DIN);
    gemm_f32<false, true,  true,  false><<<dim3(512,  8), blk, 0, stream>>>(upd_p, W1, b1, nullptr, upd_n, N_ROWS, HID,    HID);
    gemm_f32<false, true,  true,  false><<<dim3(512,  8), blk, 0, stream>>>(upd_n, W2, b2, nullptr, h,     N_ROWS, HID,    HID);
    // score = h @ K^T -> sq region
    gemm_f32<true,  false, false, false><<<dim3(512, 16), blk, 0, stream>>>(h,     Km, nullptr, nullptr, sq, N_ROWS, MSLOTS, HID);

    // row softmaxes (+/-) and argmax/rowmax
    row_softmax<<<dim3(32768), blk, 0, stream>>>(sq, sm, usm, g, rowmax);

    // column stats
    col_minmax      <<<dim3(16, 32), blk, 0, stream>>>(sq, pA, pB);
    col_stage2_minmax<<<dim3(4),     blk, 0, stream>>>(pA, pB, m_pos, m_neg);
    col_sum         <<<dim3(16, 32), blk, 0, stream>>>(sq, m_pos, m_neg, pA, pB);
    col_stage2_sum  <<<dim3(4),      blk, 0, stream>>>(pA, pB, s_pos, s_neg);

    // memory update (needs m_pos; does not need sq values)
    hipMemsetAsync(qu, 0, (size_t)MSLOTS * HID * sizeof(float), stream);
    scatter_qu<<<dim3(32768), blk, 0, stream>>>(h, g, rowmax, m_pos, qu);
    norm_mem  <<<dim3(1024),  blk, 0, stream>>>(qu, Km, new_mem);

    // usq + sq (in-place over score) — after all score consumers are done
    col_write<<<dim3(32768), blk, 0, stream>>>(sq, usq, m_pos, s_pos, m_neg, s_neg);

    // reads: upd = h * (P @ K)
    gemm_f32<false, false, false, true><<<dim3(512, 8), blk, 0, stream>>>(sm,  Km, nullptr, h, upd_p, N_ROWS, HID, MSLOTS);
    gemm_f32<false, false, false, true><<<dim3(512, 8), blk, 0, stream>>>(usm, Km, nullptr, h, upd_n, N_ROWS, HID, MSLOTS);

    // pred head
    pred_k<<<dim3(8192), blk, 0, stream>>>(h, Wd, bd, pred);
}

// Round 2
// 1720.918 us; speedup vs baseline: 1.8197x; 1.8197x over previous
//
#include <hip/hip_runtime.h>
#include <float.h>
#include <math.h>

#define N_ROWS 32768
#define DIN    360
#define DINP   384
#define HID    512
#define MSLOTS 1024

typedef __attribute__((ext_vector_type(8))) short short8;
typedef __attribute__((ext_vector_type(4))) float f32x4;

__device__ __forceinline__ ushort f2bf(float f) {
    uint u = __float_as_uint(f);
    uint r = (u + 0x7FFF + ((u >> 16) & 1)) >> 16;
    return (ushort)r;
}
__device__ __forceinline__ float bf2f(ushort h) {
    return __uint_as_float(((uint)h) << 16);
}

typedef const __attribute__((address_space(1))) void* gas_ptr;
typedef __attribute__((address_space(3))) void* las_ptr;
__device__ __forceinline__ void stage16(const void* g, void* l) {
    __builtin_amdgcn_global_load_lds((gas_ptr)g, (las_ptr)l, 16, 0, 0);
}

// ---------------- split/pad f32 -> bf16 hi/lo, optional zero-pad cols ----------------
__global__ __launch_bounds__(256) void split_pad_k(
    const float* __restrict__ in, ushort* __restrict__ hi, ushort* __restrict__ lo,
    int R, int C, int Cp)
{
    size_t idx = (size_t)blockIdx.x * 256 + threadIdx.x;
    if (idx >= (size_t)R * Cp) return;
    int r = (int)(idx / Cp), c = (int)(idx % Cp);
    float v = (c < C) ? in[(size_t)r * C + c] : 0.f;
    ushort h = f2bf(v);
    hi[idx] = h;
    lo[idx] = f2bf(v - bf2f(h));
}

// ---------------- transpose+split: in [K][N] f32 -> out [N][Kp] bf16 hi/lo ----------------
__global__ __launch_bounds__(256) void tsplit_k(
    const float* __restrict__ in, ushort* __restrict__ hiT, ushort* __restrict__ loT,
    int K, int N, int Kp)
{
    size_t idx = (size_t)blockIdx.x * 256 + threadIdx.x;
    if (idx >= (size_t)N * Kp) return;
    int n = (int)(idx / Kp), k = (int)(idx % Kp);
    float v = (k < K) ? in[(size_t)k * N + n] : 0.f;
    ushort h = f2bf(v);
    hiT[idx] = h;
    loT[idx] = f2bf(v - bf2f(h));
}

// ---------------- MFMA GEMM: C = epi(A @ B^T), A [M][K] bf16 (hi/lo), B [N][K] bf16 ----------------
// 128x128 tile, BK=32, 256 thr (4 waves 2x2), 4x4 16x16x32 frags per wave.
template<bool SPLIT, bool BIAS, bool RELU, bool HMUL, bool WF32, bool WSPLIT>
__global__ __launch_bounds__(256) void gemm_mfma(
    const ushort* __restrict__ Ah, const ushort* __restrict__ Al,
    const ushort* __restrict__ Bh, const ushort* __restrict__ Bl,
    const float* __restrict__ bias, const float* __restrict__ hm,
    float* __restrict__ C, ushort* __restrict__ Oh, ushort* __restrict__ Ol,
    int M, int N, int K)
{
    __shared__ ushort As[2][128 * 32];
    __shared__ ushort Bs[2][128 * 32];
    const int tid = threadIdx.x;
    const int lane = tid & 63, wid = tid >> 6;
    const int wr = wid >> 1, wc = wid & 1;
    const int m0 = blockIdx.x * 128, n0 = blockIdx.y * 128;

    f32x4 acc[4][4];
    #pragma unroll
    for (int i = 0; i < 4; ++i)
        #pragma unroll
        for (int j = 0; j < 4; ++j)
            acc[i][j] = (f32x4){0.f, 0.f, 0.f, 0.f};

    const int srow = lane >> 2;          // row within 16-row segment
    const int scol = (lane & 3) * 8;     // element col within BK=32
    const int seg0 = wid * 2;
    const int ka = (lane >> 4) * 8;
    const int l15 = lane & 15;

    for (int k0 = 0; k0 < K; k0 += 32) {
        #pragma unroll
        for (int q = 0; q < 2; ++q) {
            const int seg = seg0 + q;
            const int row = seg * 16 + srow;
            stage16(Ah + (size_t)(m0 + row) * K + k0 + scol, &As[0][seg * 512]);
            stage16(Bh + (size_t)(n0 + row) * K + k0 + scol, &Bs[0][seg * 512]);
            if (SPLIT) {
                stage16(Al + (size_t)(m0 + row) * K + k0 + scol, &As[1][seg * 512]);
                stage16(Bl + (size_t)(n0 + row) * K + k0 + scol, &Bs[1][seg * 512]);
            }
        }
        __syncthreads();
        short8 ah[4], bh[4], al[4], bl[4];
        #pragma unroll
        for (int f = 0; f < 4; ++f) {
            const int ra = wr * 64 + f * 16 + l15;
            const int rb = wc * 64 + f * 16 + l15;
            ah[f] = *(const short8*)&As[0][ra * 32 + ka];
            bh[f] = *(const short8*)&Bs[0][rb * 32 + ka];
            if (SPLIT) {
                al[f] = *(const short8*)&As[1][ra * 32 + ka];
                bl[f] = *(const short8*)&Bs[1][rb * 32 + ka];
            }
        }
        #pragma unroll
        for (int i = 0; i < 4; ++i)
            #pragma unroll
            for (int j = 0; j < 4; ++j) {
                acc[i][j] = __builtin_amdgcn_mfma_f32_16x16x32_bf16(ah[i], bh[j], acc[i][j], 0, 0, 0);
                if (SPLIT) {
                    acc[i][j] = __builtin_amdgcn_mfma_f32_16x16x32_bf16(ah[i], bl[j], acc[i][j], 0, 0, 0);
                    acc[i][j] = __builtin_amdgcn_mfma_f32_16x16x32_bf16(al[i], bh[j], acc[i][j], 0, 0, 0);
                }
            }
        __syncthreads();
    }

    #pragma unroll
    for (int i = 0; i < 4; ++i) {
        #pragma unroll
        for (int j = 0; j < 4; ++j) {
            const int col = n0 + wc * 64 + j * 16 + l15;
            #pragma unroll
            for (int r = 0; r < 4; ++r) {
                const int row = m0 + wr * 64 + i * 16 + (lane >> 4) * 4 + r;
                float v = acc[i][j][r];
                if (BIAS) v += bias[col];
                if (RELU) v = fmaxf(v, 0.f);
                if (HMUL) v *= hm[(size_t)row * N + col];
                if (WF32) C[(size_t)row * N + col] = v;
                if (WSPLIT) {
                    ushort hi_ = f2bf(v);
                    Oh[(size_t)row * N + col] = hi_;
                    Ol[(size_t)row * N + col] = f2bf(v - bf2f(hi_));
                }
            }
        }
    }
}

// ---------------- row softmax (axis=1) of +score and -score (+bf16 copies) ----------------
__global__ __launch_bounds__(256) void row_softmax(
    const float* __restrict__ score, float* __restrict__ sm, float* __restrict__ usm,
    ushort* __restrict__ smh, ushort* __restrict__ usmh,
    int* __restrict__ g, float* __restrict__ rowmax)
{
    const int row = blockIdx.x, t = threadIdx.x;
    const float4 v = ((const float4*)(score + (size_t)row * MSLOTS))[t];
    float mx = v.x; int mi = t * 4;
    if (v.y > mx) { mx = v.y; mi = t * 4 + 1; }
    if (v.z > mx) { mx = v.z; mi = t * 4 + 2; }
    if (v.w > mx) { mx = v.w; mi = t * 4 + 3; }
    float mn = fminf(fminf(v.x, v.y), fminf(v.z, v.w));
    __shared__ float rf[256]; __shared__ int ri[256]; __shared__ float rn[256];
    rf[t] = mx; ri[t] = mi; rn[t] = mn;
    __syncthreads();
    for (int s = 128; s > 0; s >>= 1) {
        if (t < s) {
            float o = rf[t + s]; int oi = ri[t + s];
            if (o > rf[t] || (o == rf[t] && oi < ri[t])) { rf[t] = o; ri[t] = oi; }
            rn[t] = fminf(rn[t], rn[t + s]);
        }
        __syncthreads();
    }
    const float rmx = rf[0]; const int gi = ri[0]; const float rmn = rn[0];
    __syncthreads();
    const float e0 = expf(v.x - rmx), e1 = expf(v.y - rmx), e2 = expf(v.z - rmx), e3 = expf(v.w - rmx);
    const float u0 = expf(rmn - v.x), u1 = expf(rmn - v.y), u2 = expf(rmn - v.z), u3 = expf(rmn - v.w);
    rf[t] = e0 + e1 + e2 + e3; rn[t] = u0 + u1 + u2 + u3;
    __syncthreads();
    for (int s = 128; s > 0; s >>= 1) {
        if (t < s) { rf[t] += rf[t + s]; rn[t] += rn[t + s]; }
        __syncthreads();
    }
    const float isp = 1.0f / rf[0], isn = 1.0f / rn[0];
    const float4 so = make_float4(e0 * isp, e1 * isp, e2 * isp, e3 * isp);
    const float4 uo = make_float4(u0 * isn, u1 * isn, u2 * isn, u3 * isn);
    ((float4*)(sm + (size_t)row * MSLOTS))[t] = so;
    ((float4*)(usm + (size_t)row * MSLOTS))[t] = uo;
    ushort4 sh = make_ushort4(f2bf(so.x), f2bf(so.y), f2bf(so.z), f2bf(so.w));
    ushort4 uh = make_ushort4(f2bf(uo.x), f2bf(uo.y), f2bf(uo.z), f2bf(uo.w));
    ((ushort4*)(smh + (size_t)row * MSLOTS))[t] = sh;
    ((ushort4*)(usmh + (size_t)row * MSLOTS))[t] = uh;
    if (t == 0) { g[row] = gi; rowmax[row] = rmx; }
}

// ---------------- column stats ----------------
__global__ __launch_bounds__(256) void col_minmax(
    const float* __restrict__ score, float* __restrict__ pmax, float* __restrict__ pmin)
{
    const int c = threadIdx.x & 63;
    const int col = blockIdx.x * 64 + c;
    const int tr = threadIdx.x >> 6;
    const int row0 = blockIdx.y * 1024;
    float mx = -FLT_MAX, mn = FLT_MAX;
    for (int k = 0; k < 256; ++k) {
        const float s = score[(size_t)(row0 + tr + k * 4) * MSLOTS + col];
        mx = fmaxf(mx, s); mn = fminf(mn, s);
    }
    __shared__ float smx[4][64], smn[4][64];
    smx[tr][c] = mx; smn[tr][c] = mn;
    __syncthreads();
    if (tr == 0) {
        #pragma unroll
        for (int i = 1; i < 4; ++i) { mx = fmaxf(mx, smx[i][c]); mn = fminf(mn, smn[i][c]); }
        pmax[(size_t)blockIdx.y * MSLOTS + col] = mx;
        pmin[(size_t)blockIdx.y * MSLOTS + col] = mn;
    }
}

__global__ __launch_bounds__(256) void col_stage2_minmax(
    const float* __restrict__ pmax, const float* __restrict__ pmin,
    float* __restrict__ m_pos, float* __restrict__ m_neg)
{
    const int col = blockIdx.x * 256 + threadIdx.x;
    float mx = -FLT_MAX, mn = FLT_MAX;
    for (int k = 0; k < 32; ++k) {
        mx = fmaxf(mx, pmax[(size_t)k * MSLOTS + col]);
        mn = fminf(mn, pmin[(size_t)k * MSLOTS + col]);
    }
    m_pos[col] = mx;
    m_neg[col] = -mn;
}

__global__ __launch_bounds__(256) void col_sum(
    const float* __restrict__ score, const float* __restrict__ m_pos,
    const float* __restrict__ m_neg, float* __restrict__ psum, float* __restrict__ pnsum)
{
    const int c = threadIdx.x & 63;
    const int col = blockIdx.x * 64 + c;
    const int tr = threadIdx.x >> 6;
    const int row0 = blockIdx.y * 1024;
    const float mp = m_pos[col], mg = m_neg[col];
    float sp = 0.f, sn = 0.f;
    for (int k = 0; k < 256; ++k) {
        const float s = score[(size_t)(row0 + tr + k * 4) * MSLOTS + col];
        sp += expf(s - mp);
        sn += expf(-s - mg);
    }
    __shared__ float s1[4][64], s2[4][64];
    s1[tr][c] = sp; s2[tr][c] = sn;
    __syncthreads();
    if (tr == 0) {
        #pragma unroll
        for (int i = 1; i < 4; ++i) { sp += s1[i][c]; sn += s2[i][c]; }
        psum [(size_t)blockIdx.y * MSLOTS + col] = sp;
        pnsum[(size_t)blockIdx.y * MSLOTS + col] = sn;
    }
}

__global__ __launch_bounds__(256) void col_stage2_sum(
    const float* __restrict__ ps, const float* __restrict__ pn,
    float* __restrict__ s_pos, float* __restrict__ s_neg)
{
    const int col = blockIdx.x * 256 + threadIdx.x;
    float a = 0.f, b = 0.f;
    for (int k = 0; k < 32; ++k) { a += ps[(size_t)k * MSLOTS + col]; b += pn[(size_t)k * MSLOTS + col]; }
    s_pos[col] = a; s_neg[col] = b;
}

__global__ __launch_bounds__(256) void col_write(
    float* __restrict__ score_sq, float* __restrict__ usq,
    const float* __restrict__ m_pos, const float* __restrict__ s_pos,
    const float* __restrict__ m_neg, const float* __restrict__ s_neg)
{
    const size_t idx = (size_t)blockIdx.x * 256 + threadIdx.x;
    const int col = (int)((idx & 255) * 4);
    const float4 s = ((const float4*)score_sq)[idx];
    float4 q, uq;
    q.x  = expf( s.x - m_pos[col + 0]) / s_pos[col + 0];
    q.y  = expf( s.y - m_pos[col + 1]) / s_pos[col + 1];
    q.z  = expf( s.z - m_pos[col + 2]) / s_pos[col + 2];
    q.w  = expf( s.w - m_pos[col + 3]) / s_pos[col + 3];
    uq.x = expf(-s.x - m_neg[col + 0]) / s_neg[col + 0];
    uq.y = expf(-s.y - m_neg[col + 1]) / s_neg[col + 1];
    uq.z = expf(-s.z - m_neg[col + 2]) / s_neg[col + 2];
    uq.w = expf(-s.w - m_neg[col + 3]) / s_neg[col + 3];
    ((float4*)usq)[idx] = uq;
    ((float4*)score_sq)[idx] = q;
}

__global__ __launch_bounds__(256) void scatter_qu(
    const float* __restrict__ h, const int* __restrict__ g,
    const float* __restrict__ rowmax, const float* __restrict__ m_pos,
    float* __restrict__ qu)
{
    const int row = blockIdx.x, t = threadIdx.x;
    const int gi = g[row];
    const float w = expf(rowmax[row] - m_pos[gi]);
    const float2 hv = ((const float2*)(h + (size_t)row * HID))[t];
    atomicAdd(&qu[(size_t)gi * HID + t * 2 + 0], w * hv.x);
    atomicAdd(&qu[(size_t)gi * HID + t * 2 + 1], w * hv.y);
}

__global__ __launch_bounds__(256) void norm_mem(
    const float* __restrict__ qu, const float* __restrict__ Km, float* __restrict__ nm)
{
    const int j = blockIdx.x, t = threadIdx.x;
    const float2 q = ((const float2*)(qu + (size_t)j * HID))[t];
    const float2 k = ((const float2*)(Km + (size_t)j * HID))[t];
    const float vx = q.x + k.x, vy = q.y + k.y;
    __shared__ float red[256];
    red[t] = vx * vx + vy * vy;
    __syncthreads();
    for (int s = 128; s > 0; s >>= 1) {
        if (t < s) red[t] += red[t + s];
        __syncthreads();
    }
    const float inv = 1.0f / fmaxf(sqrtf(red[0]), 1e-12f);
    ((float2*)(nm + (size_t)j * HID))[t] = make_float2(vx * inv, vy * inv);
}

__global__ __launch_bounds__(256) void pred_k(
    const float* __restrict__ h, const float* __restrict__ Wd,
    const float* __restrict__ bd, float* __restrict__ pred)
{
    const int lane = threadIdx.x & 63, wv = threadIdx.x >> 6;
    const int row = blockIdx.x * 4 + wv;
    const float* hr = h + (size_t)row * HID + lane * 8;
    const float* wr = Wd + lane * 8;
    float a = 0.f;
    #pragma unroll
    for (int k = 0; k < 8; ++k) a = fmaf(hr[k], wr[k], a);
    for (int o = 32; o > 0; o >>= 1) a += __shfl_down(a, o, 64);
    if (lane == 0) pred[row] = a + bd[0];
}

extern "C" void kernel_launch(void* const* d_in, const int* in_sizes, int n_in,
                              void* d_out, int out_size, void* d_ws, size_t ws_size,
                              hipStream_t stream)
{
    const float* x  = (const float*)d_in[0];
    const float* Km = (const float*)d_in[1];
    const float* W0 = (const float*)d_in[2];
    const float* b0 = (const float*)d_in[3];
    const float* W1 = (const float*)d_in[4];
    const float* b1 = (const float*)d_in[5];
    const float* W2 = (const float*)d_in[6];
    const float* b2 = (const float*)d_in[7];
    const float* Wd = (const float*)d_in[8];
    const float* bd = (const float*)d_in[9];

    float* out      = (float*)d_out;
    float* pred     = out;
    float* upd_n    = out + 32768;
    float* usq      = upd_n + (size_t)N_ROWS * HID;
    float* usm      = usq   + (size_t)N_ROWS * MSLOTS;
    float* upd_p    = usm   + (size_t)N_ROWS * MSLOTS;
    float* sq       = upd_p + (size_t)N_ROWS * HID;     // holds score until col_write
    float* sm       = sq    + (size_t)N_ROWS * MSLOTS;
    float* new_mem  = sm    + (size_t)N_ROWS * MSLOTS;

    char* wp = (char*)d_ws;
    float* h      = (float*)wp;  wp += (size_t)N_ROWS * HID * 4;            // 67 MB
    ushort* S1    = (ushort*)wp; wp += (size_t)N_ROWS * HID * 2 * 2;        // 67 MB region
    ushort* S2    = (ushort*)wp; wp += (size_t)N_ROWS * HID * 2 * 2;        // 67 MB region
    ushort* w0t_h = (ushort*)wp; wp += (size_t)HID * DINP * 2;
    ushort* w0t_l = (ushort*)wp; wp += (size_t)HID * DINP * 2;
    ushort* w1t_h = (ushort*)wp; wp += (size_t)HID * HID * 2;
    ushort* w1t_l = (ushort*)wp; wp += (size_t)HID * HID * 2;
    ushort* w2t_h = (ushort*)wp; wp += (size_t)HID * HID * 2;
    ushort* w2t_l = (ushort*)wp; wp += (size_t)HID * HID * 2;
    ushort* km_h  = (ushort*)wp; wp += (size_t)MSLOTS * HID * 2;
    ushort* km_l  = (ushort*)wp; wp += (size_t)MSLOTS * HID * 2;
    ushort* kmT_h = (ushort*)wp; wp += (size_t)HID * MSLOTS * 2;
    ushort* kmT_l = (ushort*)wp; wp += (size_t)HID * MSLOTS * 2;
    float* qu     = (float*)wp;  wp += (size_t)MSLOTS * HID * 4;
    float* pA     = (float*)wp;  wp += (size_t)32 * MSLOTS * 4;
    float* pB     = (float*)wp;  wp += (size_t)32 * MSLOTS * 4;
    float* m_pos  = (float*)wp;  wp += MSLOTS * 4;
    float* s_pos  = (float*)wp;  wp += MSLOTS * 4;
    float* m_neg  = (float*)wp;  wp += MSLOTS * 4;
    float* s_neg  = (float*)wp;  wp += MSLOTS * 4;
    float* rowmax = (float*)wp;  wp += (size_t)N_ROWS * 4;
    int*   g      = (int*)wp;    wp += (size_t)N_ROWS * 4;

    // region overlays
    ushort* x_h   = S1;                               // [N][384]
    ushort* x_l   = S1 + (size_t)N_ROWS * DINP;
    ushort* h1_h  = S1;                               // [N][512]
    ushort* h1_l  = S1 + (size_t)N_ROWS * HID;
    ushort* smh   = S1;                               // [N][1024] bf16
    ushort* usmh  = S1 + (size_t)N_ROWS * MSLOTS;
    ushort* h0_h  = S2;
    ushort* h0_l  = S2 + (size_t)N_ROWS * HID;
    ushort* hs_h  = S2;                               // final h split
    ushort* hs_l  = S2 + (size_t)N_ROWS * HID;

    const dim3 blk(256);

    // --- conversions ---
    split_pad_k<<<dim3((N_ROWS * DINP + 255) / 256), blk, 0, stream>>>(x, x_h, x_l, N_ROWS, DIN, DINP);
    tsplit_k<<<dim3((HID * DINP + 255) / 256), blk, 0, stream>>>(W0, w0t_h, w0t_l, DIN, HID, DINP);
    tsplit_k<<<dim3((HID * HID + 255) / 256), blk, 0, stream>>>(W1, w1t_h, w1t_l, HID, HID, HID);
    tsplit_k<<<dim3((HID * HID + 255) / 256), blk, 0, stream>>>(W2, w2t_h, w2t_l, HID, HID, HID);
    split_pad_k<<<dim3((MSLOTS * HID + 255) / 256), blk, 0, stream>>>(Km, km_h, km_l, MSLOTS, HID, HID);
    tsplit_k<<<dim3((HID * MSLOTS + 255) / 256), blk, 0, stream>>>(Km, kmT_h, kmT_l, MSLOTS, HID, MSLOTS);

    // --- MLP (split bf16, f32-accurate) ---
    gemm_mfma<true, true, true, false, false, true><<<dim3(256, 4), blk, 0, stream>>>(
        x_h, x_l, w0t_h, w0t_l, b0, nullptr, nullptr, h0_h, h0_l, N_ROWS, HID, DINP);
    gemm_mfma<true, true, true, false, false, true><<<dim3(256, 4), blk, 0, stream>>>(
        h0_h, h0_l, w1t_h, w1t_l, b1, nullptr, nullptr, h1_h, h1_l, N_ROWS, HID, HID);
    gemm_mfma<true, true, true, false, true, true><<<dim3(256, 4), blk, 0, stream>>>(
        h1_h, h1_l, w2t_h, w2t_l, b2, nullptr, h, hs_h, hs_l, N_ROWS, HID, HID);

    // --- score = h @ Km^T (split) -> sq region ---
    gemm_mfma<true, false, false, false, true, false><<<dim3(256, 8), blk, 0, stream>>>(
        hs_h, hs_l, km_h, km_l, nullptr, nullptr, sq, nullptr, nullptr, N_ROWS, MSLOTS, HID);

    // --- row softmaxes + argmax/rowmax (also bf16 copies into S1) ---
    row_softmax<<<dim3(32768), blk, 0, stream>>>(sq, sm, usm, smh, usmh, g, rowmax);

    // --- column stats ---
    col_minmax       <<<dim3(16, 32), blk, 0, stream>>>(sq, pA, pB);
    col_stage2_minmax<<<dim3(4),      blk, 0, stream>>>(pA, pB, m_pos, m_neg);
    col_sum          <<<dim3(16, 32), blk, 0, stream>>>(sq, m_pos, m_neg, pA, pB);
    col_stage2_sum   <<<dim3(4),      blk, 0, stream>>>(pA, pB, s_pos, s_neg);

    // --- memory update ---
    hipMemsetAsync(qu, 0, (size_t)MSLOTS * HID * sizeof(float), stream);
    scatter_qu<<<dim3(32768), blk, 0, stream>>>(h, g, rowmax, m_pos, qu);
    norm_mem  <<<dim3(1024),  blk, 0, stream>>>(qu, Km, new_mem);

    // --- usq + sq (in-place) ---
    col_write<<<dim3(32768), blk, 0, stream>>>(sq, usq, m_pos, s_pos, m_neg, s_neg);

    // --- reads: upd = h * (P @ Km), plain bf16 ---
    gemm_mfma<false, false, false, true, true, false><<<dim3(256, 4), blk, 0, stream>>>(
        smh, nullptr, kmT_h, nullptr, nullptr, h, upd_p, nullptr, nullptr, N_ROWS, HID, MSLOTS);
    gemm_mfma<false, false, false, true, true, false><<<dim3(256, 4), blk, 0, stream>>>(
        usmh, nullptr, kmT_h, nullptr, nullptr, h, upd_n, nullptr, nullptr, N_ROWS, HID, MSLOTS);

    // --- pred head ---
    pred_k<<<dim3(8192), blk, 0, stream>>>(h, Wd, bd, pred);
}